// Round 3
// baseline (61.069 us; speedup 1.0000x reference)
//
#include <hip/hip_runtime.h>

// Problem constants (from setup_inputs): B=16, C=320, H=W=64, G=5, Cg=64
#define BATCH 16
#define CHAN  320
#define HH    64
#define WW    64
#define PLANE (HH*WW)            // 4096
#define NGRP  5
#define CG    64                 // CHAN / NGRP

// Static device scratch (module-load allocated; avoids any dependence on
// ws_size). Fully overwritten before being read on every kernel_launch call.
__device__ float g_em[BATCH * PLANE];   // channel SUM of edge_guidance
__device__ float g_w0[BATCH * PLANE];   // softmax weight for the H-shift term

// ---------------------------------------------------------------------------
// Kernel 1: g_em[b,r,q] = sum_c edge_guidance[b,c,r,q]
// grid = B*H blocks (1024); block = 256 = 64 q-lanes x 4 channel-chunks of 80
// ---------------------------------------------------------------------------
__global__ void k_reduce_mean(const float* __restrict__ eg)
{
    __shared__ float red[256];
    const int bid = blockIdx.x;           // b*64 + r
    const int b = bid >> 6;
    const int r = bid & 63;
    const int q   = threadIdx.x & 63;
    const int grp = threadIdx.x >> 6;     // 0..3, each owns 80 channels

    const float* p = eg + (((size_t)b * CHAN + (size_t)grp * 80) * PLANE) + r * WW + q;
    float s = 0.f;
#pragma unroll 8
    for (int c = 0; c < 80; ++c)
        s += p[(size_t)c * PLANE];

    red[threadIdx.x] = s;
    __syncthreads();
    if (grp == 0) {
        // store channel SUM; the 1/320 scale is folded into kernel 2's load
        g_em[(size_t)bid * 64 + q] = red[q] + red[q + 64] + red[q + 128] + red[q + 192];
    }
}

// ---------------------------------------------------------------------------
// Kernel 2: fused conv1(1->16,3x3)+relu -> conv2(16->2,3x3) -> softmax -> w0
// grid = B*16 blocks (one 16x16 output tile each); block = 256
// em tile staged 20x20 (halo 2), h computed per input-channel on 18x18 (halo 1)
// h is ZERO outside the 64x64 image (reference zero-pads h for conv2).
// ---------------------------------------------------------------------------
__global__ void k_conv_dir(const float* __restrict__ w1, const float* __restrict__ b1,
                           const float* __restrict__ w2, const float* __restrict__ b2)
{
    __shared__ float sem[20][20];
    __shared__ float shh[18][18];
    __shared__ float sw1[16][9];
    __shared__ float sb1[16];
    __shared__ float sw2[2][16][9];
    __shared__ float sb2[2];

    const int bid = blockIdx.x;
    const int b  = bid >> 4;
    const int t  = bid & 15;
    const int r0 = (t >> 2) * 16;
    const int q0 = (t & 3) * 16;
    const int tid = threadIdx.x;

    if (tid < 144) sw1[tid / 9][tid % 9] = w1[tid];
    if (tid < 16)  sb1[tid] = b1[tid];
    // 288 elements > 256 threads: MUST be strided (bug fixed: elements
    // 256..287 were previously uninitialized LDS -> saturated softmax)
    for (int i = tid; i < 288; i += 256) ((float*)sw2)[i] = w2[i];
    if (tid < 2)   sb2[tid] = b2[tid];

    const float scale = 1.0f / (float)CHAN;
    for (int i = tid; i < 400; i += 256) {
        const int lr = i / 20, lq = i % 20;
        const int r = r0 + lr - 2, q = q0 + lq - 2;
        float v = 0.f;
        if ((unsigned)r < HH && (unsigned)q < WW)
            v = g_em[((size_t)b * HH + r) * WW + q] * scale;
        sem[lr][lq] = v;
    }
    __syncthreads();

    const int lr = tid >> 4;   // output pixel within 16x16 tile
    const int lq = tid & 15;
    float l0 = sb2[0];
    float l1 = sb2[1];

    for (int i = 0; i < 16; ++i) {
        // h_i on the 18x18 halo region; zero outside the image
        for (int p = tid; p < 324; p += 256) {
            const int hr = p / 18, hq = p % 18;
            const int gr = r0 - 1 + hr, gq = q0 - 1 + hq;
            float acc = 0.f;
            if ((unsigned)gr < HH && (unsigned)gq < WW) {
                acc = sb1[i];
#pragma unroll
                for (int dr = 0; dr < 3; ++dr)
#pragma unroll
                    for (int dq = 0; dq < 3; ++dq)
                        acc += sem[hr + dr][hq + dq] * sw1[i][dr * 3 + dq];
                acc = fmaxf(acc, 0.f);
            }
            shh[hr][hq] = acc;
        }
        __syncthreads();
#pragma unroll
        for (int dr = 0; dr < 3; ++dr)
#pragma unroll
            for (int dq = 0; dq < 3; ++dq) {
                const float hv = shh[lr + dr][lq + dq];
                l0 += hv * sw2[0][i][dr * 3 + dq];
                l1 += hv * sw2[1][i][dr * 3 + dq];
            }
        __syncthreads();
    }

    const float m  = fmaxf(l0, l1);
    const float e0 = expf(l0 - m);
    const float e1 = expf(l1 - m);
    const float w0v = e0 / (e0 + e1);
    g_w0[((size_t)b * HH + (r0 + lr)) * WW + (q0 + lq)] = w0v;
}

// ---------------------------------------------------------------------------
// Kernel 3: out[b,c,r,q] = w0[b,r,q]*X(r-sh[g],q) + (1-w0[b,r,q])*X(r,q-sw[g])
// grid = B*C blocks (one 64x64 plane each); block = 256; 4 float4 per thread
// ---------------------------------------------------------------------------
__global__ void k_shift_blend(const float* __restrict__ x,
                              const int* __restrict__ sh_arr, const int* __restrict__ sw_arr,
                              float* __restrict__ out)
{
    const int bid = blockIdx.x;           // b*CHAN + c
    const int c = bid % CHAN;
    const int b = bid / CHAN;
    const int g = c >> 6;                 // CG = 64
    const int sh = sh_arr[g];
    const int sw = sw_arr[g];

    const float* xp = x    + (size_t)bid * PLANE;
    const float* wp = g_w0 + (size_t)b * PLANE;
    float*       op = out  + (size_t)bid * PLANE;

#pragma unroll
    for (int j = 0; j < 4; ++j) {
        const int p4 = threadIdx.x + j * 256;   // float4 index within plane (0..1023)
        const int r  = p4 >> 4;
        const int q  = (p4 & 15) * 4;

        const float4 wv = ((const float4*)wp)[p4];

        float4 xh = make_float4(0.f, 0.f, 0.f, 0.f);
        const int rs = r - sh;
        if ((unsigned)rs < HH)
            xh = ((const float4*)(xp + (size_t)rs * WW))[p4 & 15];

        float xw[4];
#pragma unroll
        for (int k = 0; k < 4; ++k) {
            const int qs = q + k - sw;
            xw[k] = ((unsigned)qs < WW) ? xp[r * WW + qs] : 0.f;
        }

        float4 o;
        o.x = wv.x * xh.x + (1.f - wv.x) * xw[0];
        o.y = wv.y * xh.y + (1.f - wv.y) * xw[1];
        o.z = wv.z * xh.z + (1.f - wv.z) * xw[2];
        o.w = wv.w * xh.w + (1.f - wv.w) * xw[3];
        ((float4*)op)[p4] = o;
    }
}

extern "C" void kernel_launch(void* const* d_in, const int* in_sizes, int n_in,
                              void* d_out, int out_size, void* d_ws, size_t ws_size,
                              hipStream_t stream)
{
    const float* x   = (const float*)d_in[0];
    const float* eg  = (const float*)d_in[1];
    const float* w1  = (const float*)d_in[2];
    const float* b1  = (const float*)d_in[3];
    const float* w2  = (const float*)d_in[4];
    const float* b2  = (const float*)d_in[5];
    const int*   shh = (const int*)d_in[6];
    const int*   shw = (const int*)d_in[7];
    float* out = (float*)d_out;

    k_reduce_mean<<<BATCH * HH, 256, 0, stream>>>(eg);
    k_conv_dir<<<BATCH * 16, 256, 0, stream>>>(w1, b1, w2, b2);
    k_shift_blend<<<BATCH * CHAN, 256, 0, stream>>>(x, shh, shw, out);
}

// Round 4
// 58.266 us; speedup vs baseline: 1.0481x; 1.0481x over previous
//
#include <hip/hip_runtime.h>

// Problem constants (from setup_inputs): B=16, C=320, H=W=64, G=5, Cg=64
#define BATCH 16
#define CHAN  320
#define HH    64
#define WW    64
#define PLANE (HH*WW)            // 4096
#define NGRP  5
#define CG    64                 // CHAN / NGRP

// Static device scratch (module-load allocated; avoids any dependence on
// ws_size). Fully overwritten before being read on every kernel_launch call.
__device__ float g_em[BATCH * PLANE];   // channel SUM of edge_guidance
__device__ float g_w0[BATCH * PLANE];   // softmax weight for the H-shift term

// ---------------------------------------------------------------------------
// Kernel 1: g_em[b,r,q] = sum_c edge_guidance[b,c,r,q]
// grid = B*H blocks (1024); block = 256 = 64 q-lanes x 4 channel-chunks of 80
// ---------------------------------------------------------------------------
__global__ void k_reduce_mean(const float* __restrict__ eg)
{
    __shared__ float red[256];
    const int bid = blockIdx.x;           // b*64 + r
    const int b = bid >> 6;
    const int r = bid & 63;
    const int q   = threadIdx.x & 63;
    const int grp = threadIdx.x >> 6;     // 0..3, each owns 80 channels

    const float* p = eg + (((size_t)b * CHAN + (size_t)grp * 80) * PLANE) + r * WW + q;
    float s = 0.f;
#pragma unroll 8
    for (int c = 0; c < 80; ++c)
        s += p[(size_t)c * PLANE];

    red[threadIdx.x] = s;
    __syncthreads();
    if (grp == 0) {
        // store channel SUM; the 1/320 scale is folded into kernel 2's load
        g_em[(size_t)bid * 64 + q] = red[q] + red[q + 64] + red[q + 128] + red[q + 192];
    }
}

// ---------------------------------------------------------------------------
// Kernel 2: fused conv1(1->16,3x3)+relu -> conv2(16->2,3x3) -> softmax -> w0
// grid = B*16 blocks (one 16x16 output tile each); block = 256
// em tile staged 20x20 (halo 2), h computed per input-channel on 18x18 (halo 1)
// h is ZERO outside the 64x64 image (reference zero-pads h for conv2).
// ---------------------------------------------------------------------------
__global__ void k_conv_dir(const float* __restrict__ w1, const float* __restrict__ b1,
                           const float* __restrict__ w2, const float* __restrict__ b2)
{
    __shared__ float sem[20][20];
    __shared__ float shh[18][18];
    __shared__ float sw1[16][9];
    __shared__ float sb1[16];
    __shared__ float sw2[2][16][9];
    __shared__ float sb2[2];

    const int bid = blockIdx.x;
    const int b  = bid >> 4;
    const int t  = bid & 15;
    const int r0 = (t >> 2) * 16;
    const int q0 = (t & 3) * 16;
    const int tid = threadIdx.x;

    if (tid < 144) sw1[tid / 9][tid % 9] = w1[tid];
    if (tid < 16)  sb1[tid] = b1[tid];
    // 288 elements > 256 threads: strided (fixed round-3 bug)
    for (int i = tid; i < 288; i += 256) ((float*)sw2)[i] = w2[i];
    if (tid < 2)   sb2[tid] = b2[tid];

    const float scale = 1.0f / (float)CHAN;
    for (int i = tid; i < 400; i += 256) {
        const int lr = i / 20, lq = i % 20;
        const int r = r0 + lr - 2, q = q0 + lq - 2;
        float v = 0.f;
        if ((unsigned)r < HH && (unsigned)q < WW)
            v = g_em[((size_t)b * HH + r) * WW + q] * scale;
        sem[lr][lq] = v;
    }
    __syncthreads();

    const int lr = tid >> 4;   // output pixel within 16x16 tile
    const int lq = tid & 15;
    float l0 = sb2[0];
    float l1 = sb2[1];

    for (int i = 0; i < 16; ++i) {
        // h_i on the 18x18 halo region; zero outside the image
        for (int p = tid; p < 324; p += 256) {
            const int hr = p / 18, hq = p % 18;
            const int gr = r0 - 1 + hr, gq = q0 - 1 + hq;
            float acc = 0.f;
            if ((unsigned)gr < HH && (unsigned)gq < WW) {
                acc = sb1[i];
#pragma unroll
                for (int dr = 0; dr < 3; ++dr)
#pragma unroll
                    for (int dq = 0; dq < 3; ++dq)
                        acc += sem[hr + dr][hq + dq] * sw1[i][dr * 3 + dq];
                acc = fmaxf(acc, 0.f);
            }
            shh[hr][hq] = acc;
        }
        __syncthreads();
#pragma unroll
        for (int dr = 0; dr < 3; ++dr)
#pragma unroll
            for (int dq = 0; dq < 3; ++dq) {
                const float hv = shh[lr + dr][lq + dq];
                l0 += hv * sw2[0][i][dr * 3 + dq];
                l1 += hv * sw2[1][i][dr * 3 + dq];
            }
        __syncthreads();
    }

    const float m  = fmaxf(l0, l1);
    const float e0 = expf(l0 - m);
    const float e1 = expf(l1 - m);
    const float w0v = e0 / (e0 + e1);
    g_w0[((size_t)b * HH + (r0 + lr)) * WW + (q0 + lq)] = w0v;
}

// ---------------------------------------------------------------------------
// Kernel 3: out[b,c,r,q] = w0[b,r,q]*X(r-sh[g],q) + (1-w0[b,r,q])*X(r,q-sw[g])
// grid = B*C blocks (one 64x64 plane each); block = 256; 4 float4 per thread.
// x-plane staged once in LDS (coalesced float4), both shifts served from LDS.
// Row stride 68 floats: H-shift reads stay 16B-aligned ds_read_b128; W-shift
// scalar reads are 2-way bank aliased (free on CDNA4).
// ---------------------------------------------------------------------------
#define LDS_STRIDE 68
__global__ void k_shift_blend(const float* __restrict__ x,
                              const int* __restrict__ sh_arr, const int* __restrict__ sw_arr,
                              float* __restrict__ out)
{
    __shared__ float sx[HH * LDS_STRIDE];   // 64 x 68 floats = 17.4 KB

    const int bid = blockIdx.x;           // b*CHAN + c
    const int c = bid % CHAN;
    const int b = bid / CHAN;
    const int g = c >> 6;                 // CG = 64
    const int sh = sh_arr[g];
    const int sw = sw_arr[g];

    const float* xp = x    + (size_t)bid * PLANE;
    const float* wp = g_w0 + (size_t)b * PLANE;
    float*       op = out  + (size_t)bid * PLANE;

    // stage plane: 4 coalesced float4 per thread
#pragma unroll
    for (int j = 0; j < 4; ++j) {
        const int p4 = threadIdx.x + j * 256;   // float4 index (0..1023)
        const int r  = p4 >> 4;
        const int q4 = p4 & 15;
        const float4 v = ((const float4*)(xp + (size_t)r * WW))[q4];
        *(float4*)(&sx[r * LDS_STRIDE + q4 * 4]) = v;
    }
    __syncthreads();

#pragma unroll
    for (int j = 0; j < 4; ++j) {
        const int p4 = threadIdx.x + j * 256;
        const int r  = p4 >> 4;
        const int q4 = p4 & 15;
        const int q  = q4 * 4;

        const float4 wv = ((const float4*)wp)[p4];

        // H-shift: aligned float4 from LDS row (r - sh)
        float4 xh = make_float4(0.f, 0.f, 0.f, 0.f);
        const int rs = r - sh;
        if ((unsigned)rs < HH)
            xh = *(const float4*)(&sx[rs * LDS_STRIDE + q]);

        // W-shift: scalar LDS reads from row r, columns q+k-sw
        float xw[4];
#pragma unroll
        for (int k = 0; k < 4; ++k) {
            const int qs = q + k - sw;
            xw[k] = ((unsigned)qs < WW) ? sx[r * LDS_STRIDE + qs] : 0.f;
        }

        float4 o;
        o.x = wv.x * xh.x + (1.f - wv.x) * xw[0];
        o.y = wv.y * xh.y + (1.f - wv.y) * xw[1];
        o.z = wv.z * xh.z + (1.f - wv.z) * xw[2];
        o.w = wv.w * xh.w + (1.f - wv.w) * xw[3];
        ((float4*)op)[p4] = o;
    }
}

extern "C" void kernel_launch(void* const* d_in, const int* in_sizes, int n_in,
                              void* d_out, int out_size, void* d_ws, size_t ws_size,
                              hipStream_t stream)
{
    const float* x   = (const float*)d_in[0];
    const float* eg  = (const float*)d_in[1];
    const float* w1  = (const float*)d_in[2];
    const float* b1  = (const float*)d_in[3];
    const float* w2  = (const float*)d_in[4];
    const float* b2  = (const float*)d_in[5];
    const int*   shh = (const int*)d_in[6];
    const int*   shw = (const int*)d_in[7];
    float* out = (float*)d_out;

    k_reduce_mean<<<BATCH * HH, 256, 0, stream>>>(eg);
    k_conv_dir<<<BATCH * 16, 256, 0, stream>>>(w1, b1, w2, b2);
    k_shift_blend<<<BATCH * CHAN, 256, 0, stream>>>(x, shh, shw, out);
}